// Round 1
// baseline (2050.931 us; speedup 1.0000x reference)
//
#include <hip/hip_runtime.h>

// DR2FWL2 conv, MI355X. Key restructuring: mlp(e[idx]) == mlp(e)[idx], so MLPs run
// once over base rows (8*E/layer) instead of per gathered triangle row (12*T/layer).
// MLP GEMMs: MFMA 16x16x32 bf16 with hi/lo split (3 MFMAs per product, ~fp32 accuracy).
// Segment sums: fp32 global atomics, one wave per triangle.
// Workspace need: 5 * E*64 floats + ~0.6MB weights  (~193 MB for E=150000).

typedef unsigned short u16;
typedef unsigned int u32;
typedef __attribute__((ext_vector_type(8))) short s16x8;
typedef __attribute__((ext_vector_type(4))) float f32x4;

#define MFMA16(a, b, c) __builtin_amdgcn_mfma_f32_16x16x32_bf16((a), (b), (c), 0, 0, 0)

static __device__ __forceinline__ u16 bf16_rne(float x) {
  u32 u = __float_as_uint(x);
  return (u16)((u + 0x7fffu + ((u >> 16) & 1u)) >> 16);
}
static __device__ __forceinline__ float bf16_f32(u16 h) {
  return __uint_as_float(((u32)h) << 16);
}
// 8 floats (two f32x4) -> hi/lo bf16 fragments
static __device__ __forceinline__ void cvt_hilo8(const f32x4 a, const f32x4 b, s16x8& hi, s16x8& lo) {
#pragma unroll
  for (int j = 0; j < 4; j++) {
    float x = a[j];
    u16 h = bf16_rne(x);
    u16 l = bf16_rne(x - bf16_f32(h));
    hi[j] = (short)h; lo[j] = (short)l;
  }
#pragma unroll
  for (int j = 0; j < 4; j++) {
    float x = b[j];
    u16 h = bf16_rne(x);
    u16 l = bf16_rne(x - bf16_f32(h));
    hi[4 + j] = (short)h; lo[4 + j] = (short)l;
  }
}

// split fp32 weights -> bf16 hi + bf16 lo arrays
__global__ __launch_bounds__(256) void cvt_split_kernel(const float* __restrict__ src,
                                                        u16* __restrict__ hi, u16* __restrict__ lo, int n) {
  int i = blockIdx.x * 256 + threadIdx.x;
  int stride = gridDim.x * 256;
  for (; i < n; i += stride) {
    float x = src[i];
    u16 h = bf16_rne(x);
    hi[i] = h;
    lo[i] = bf16_rne(x - bf16_f32(h));
  }
}

__global__ __launch_bounds__(256) void copy_kernel(const float* __restrict__ src, float* __restrict__ dst, int n4) {
  int i = blockIdx.x * 256 + threadIdx.x;
  int stride = gridDim.x * 256;
  const f32x4* s4 = (const f32x4*)src;
  f32x4* d4 = (f32x4*)dst;
  for (; i < n4; i += stride) d4[i] = s4[i];
}

__global__ __launch_bounds__(256) void relu_kernel(float* __restrict__ e, int n4) {
  int i = blockIdx.x * 256 + threadIdx.x;
  int stride = gridDim.x * 256;
  f32x4* e4 = (f32x4*)e;
  for (; i < n4; i += stride) {
    f32x4 v = e4[i];
#pragma unroll
    for (int j = 0; j < 4; j++) v[j] = fmaxf(v[j], 0.0f);
    e4[i] = v;
  }
}

// e[r] += m[r] + m[inv[r]]   (rowwise, float4-vectorized; 16 float4 per row)
__global__ __launch_bounds__(256) void addinv_kernel(float* __restrict__ e, const float* __restrict__ m,
                                                     const int* __restrict__ inv, int E) {
  int i = blockIdx.x * 256 + threadIdx.x;
  int stride = gridDim.x * 256;
  int total = E * 16;
  const f32x4* m4 = (const f32x4*)m;
  f32x4* e4 = (f32x4*)e;
  for (; i < total; i += stride) {
    int r = i >> 4, q = i & 15;
    int ir = inv[r];
    f32x4 v = e4[i];
    f32x4 a = m4[i];
    f32x4 b = m4[(size_t)ir * 16 + q];
#pragma unroll
    for (int j = 0; j < 4; j++) v[j] += a[j] + b[j];
    e4[i] = v;
  }
}

// dst[id[t]] += pa[ia[t]] * pb[ib[t]]  (64 channels; one wave = one triangle)
__global__ __launch_bounds__(256) void seg_kernel(float* __restrict__ dst,
                                                  const float* __restrict__ pa, const float* __restrict__ pb,
                                                  const int* __restrict__ id, const int* __restrict__ ia,
                                                  const int* __restrict__ ib, int T) {
  int i = blockIdx.x * 256 + threadIdx.x;
  int stride = gridDim.x * 256;
  int total = T * 64;
  for (; i < total; i += stride) {
    int t = i >> 6, c = i & 63;
    float va = pa[(size_t)ia[t] * 64 + c];
    float vb = pb[(size_t)ib[t] * 64 + c];
    unsafeAtomicAdd(&dst[(size_t)id[t] * 64 + c], va * vb);
  }
}

// Fused 2-layer MLP: dst = relu(src @ W1 + b1) @ W2 + b2, all 64x64.
// One wave per 16-row strip. bf16 hi/lo split => ~fp32 accuracy.
// MFMA fragment layout (m89-verified): A: row=lane&15, k=8*(lane>>4)+j;
// B: col=lane&15, k=8*(lane>>4)+j;  C/D: col=lane&15, row=4*(lane>>4)+reg.
__global__ __launch_bounds__(256) void mlp_kernel(const float* __restrict__ src, float* __restrict__ dst,
                                                  const u16* __restrict__ w1h_, const u16* __restrict__ w1l_,
                                                  const u16* __restrict__ w2h_, const u16* __restrict__ w2l_,
                                                  const float* __restrict__ b1_, const float* __restrict__ b2_,
                                                  int nstrips) {
  __shared__ float hshm[4][1024];
  const int tid = threadIdx.x;
  const int wave = tid >> 6, lane = tid & 63;
  const int lrow = lane & 15, lk = lane >> 4;

  // weight fragments, resident in VGPRs for the whole kernel
  s16x8 w1h[2][4], w1l[2][4], w2h[2][4], w2l[2][4];
#pragma unroll
  for (int kt = 0; kt < 2; kt++)
#pragma unroll
    for (int nt = 0; nt < 4; nt++) {
      const int n = nt * 16 + lrow;
      const int kb = kt * 32 + lk * 8;
#pragma unroll
      for (int j = 0; j < 8; j++) {
        const int idx = (kb + j) * 64 + n;
        w1h[kt][nt][j] = (short)w1h_[idx];
        w1l[kt][nt][j] = (short)w1l_[idx];
        w2h[kt][nt][j] = (short)w2h_[idx];
        w2l[kt][nt][j] = (short)w2l_[idx];
      }
    }
  float bias1[4], bias2[4];
#pragma unroll
  for (int nt = 0; nt < 4; nt++) {
    bias1[nt] = b1_[nt * 16 + lrow];
    bias2[nt] = b2_[nt * 16 + lrow];
  }

  float* hl = hshm[wave];
  for (int s = blockIdx.x * 4 + wave; s < nstrips; s += gridDim.x * 4) {
    // A fragments of X: 8 contiguous floats per k-tile per lane, straight from global
    const float* xp = src + (size_t)(s * 16 + lrow) * 64 + lk * 8;
    f32x4 x0 = *(const f32x4*)(xp + 0);
    f32x4 x1 = *(const f32x4*)(xp + 4);
    f32x4 x2 = *(const f32x4*)(xp + 32);
    f32x4 x3 = *(const f32x4*)(xp + 36);
    s16x8 ah[2], al[2];
    cvt_hilo8(x0, x1, ah[0], al[0]);
    cvt_hilo8(x2, x3, ah[1], al[1]);

    f32x4 acc[4];
#pragma unroll
    for (int nt = 0; nt < 4; nt++) { acc[nt][0] = bias1[nt]; acc[nt][1] = bias1[nt]; acc[nt][2] = bias1[nt]; acc[nt][3] = bias1[nt]; }
#pragma unroll
    for (int kt = 0; kt < 2; kt++)
#pragma unroll
      for (int nt = 0; nt < 4; nt++) {
        acc[nt] = MFMA16(ah[kt], w1h[kt][nt], acc[nt]);
        acc[nt] = MFMA16(ah[kt], w1l[kt][nt], acc[nt]);
        acc[nt] = MFMA16(al[kt], w1h[kt][nt], acc[nt]);
      }

    // relu, then transpose through per-wave LDS tile (XOR swizzle: conflict-free writes+reads)
#pragma unroll
    for (int nt = 0; nt < 4; nt++)
#pragma unroll
      for (int r = 0; r < 4; r++) {
        const int row = lk * 4 + r;
        const int col = nt * 16 + lrow;
        hl[row * 64 + (col ^ ((row & 7) << 2))] = fmaxf(acc[nt][r], 0.0f);
      }
    s16x8 bh[2], bl[2];
#pragma unroll
    for (int kt = 0; kt < 2; kt++) {
      const int colb = kt * 32 + lk * 8;
      const int xr = (lrow & 7) << 2;
      f32x4 h0 = *(const f32x4*)&hl[lrow * 64 + ((colb + 0) ^ xr)];
      f32x4 h1 = *(const f32x4*)&hl[lrow * 64 + ((colb + 4) ^ xr)];
      cvt_hilo8(h0, h1, bh[kt], bl[kt]);
    }

    f32x4 out[4];
#pragma unroll
    for (int nt = 0; nt < 4; nt++) { out[nt][0] = bias2[nt]; out[nt][1] = bias2[nt]; out[nt][2] = bias2[nt]; out[nt][3] = bias2[nt]; }
#pragma unroll
    for (int kt = 0; kt < 2; kt++)
#pragma unroll
      for (int nt = 0; nt < 4; nt++) {
        out[nt] = MFMA16(bh[kt], w2h[kt][nt], out[nt]);
        out[nt] = MFMA16(bh[kt], w2l[kt][nt], out[nt]);
        out[nt] = MFMA16(bl[kt], w2h[kt][nt], out[nt]);
      }

    float* dp = dst + (size_t)s * 1024;
#pragma unroll
    for (int nt = 0; nt < 4; nt++)
#pragma unroll
      for (int r = 0; r < 4; r++)
        dp[(lk * 4 + r) * 64 + nt * 16 + lrow] = out[nt][r];
  }
}

// Single linear: dst = src @ W + b  (no relu)
__global__ __launch_bounds__(256) void lin_kernel(const float* __restrict__ src, float* __restrict__ dst,
                                                  const u16* __restrict__ wh_, const u16* __restrict__ wl_,
                                                  const float* __restrict__ b_, int nstrips) {
  const int tid = threadIdx.x;
  const int wave = tid >> 6, lane = tid & 63;
  const int lrow = lane & 15, lk = lane >> 4;

  s16x8 wh[2][4], wl[2][4];
#pragma unroll
  for (int kt = 0; kt < 2; kt++)
#pragma unroll
    for (int nt = 0; nt < 4; nt++) {
      const int n = nt * 16 + lrow;
      const int kb = kt * 32 + lk * 8;
#pragma unroll
      for (int j = 0; j < 8; j++) {
        const int idx = (kb + j) * 64 + n;
        wh[kt][nt][j] = (short)wh_[idx];
        wl[kt][nt][j] = (short)wl_[idx];
      }
    }
  float bias[4];
#pragma unroll
  for (int nt = 0; nt < 4; nt++) bias[nt] = b_[nt * 16 + lrow];

  for (int s = blockIdx.x * 4 + wave; s < nstrips; s += gridDim.x * 4) {
    const float* xp = src + (size_t)(s * 16 + lrow) * 64 + lk * 8;
    f32x4 x0 = *(const f32x4*)(xp + 0);
    f32x4 x1 = *(const f32x4*)(xp + 4);
    f32x4 x2 = *(const f32x4*)(xp + 32);
    f32x4 x3 = *(const f32x4*)(xp + 36);
    s16x8 ah[2], al[2];
    cvt_hilo8(x0, x1, ah[0], al[0]);
    cvt_hilo8(x2, x3, ah[1], al[1]);

    f32x4 acc[4];
#pragma unroll
    for (int nt = 0; nt < 4; nt++) { acc[nt][0] = bias[nt]; acc[nt][1] = bias[nt]; acc[nt][2] = bias[nt]; acc[nt][3] = bias[nt]; }
#pragma unroll
    for (int kt = 0; kt < 2; kt++)
#pragma unroll
      for (int nt = 0; nt < 4; nt++) {
        acc[nt] = MFMA16(ah[kt], wh[kt][nt], acc[nt]);
        acc[nt] = MFMA16(ah[kt], wl[kt][nt], acc[nt]);
        acc[nt] = MFMA16(al[kt], wh[kt][nt], acc[nt]);
      }
    float* dp = dst + (size_t)s * 1024;
#pragma unroll
    for (int nt = 0; nt < 4; nt++)
#pragma unroll
      for (int r = 0; r < 4; r++)
        dp[(lk * 4 + r) * 64 + nt * 16 + lrow] = acc[nt][r];
  }
}

extern "C" void kernel_launch(void* const* d_in, const int* in_sizes, int n_in,
                              void* d_out, int out_size, void* d_ws, size_t ws_size,
                              hipStream_t stream) {
  const float* in_e1 = (const float*)d_in[0];
  const float* in_e2 = (const float*)d_in[1];
  const int* t111 = (const int*)d_in[2];
  const int* t112 = (const int*)d_in[3];
  const int* t122 = (const int*)d_in[4];
  const int* t222 = (const int*)d_in[5];
  const int* inv1 = (const int*)d_in[6];
  const int* inv2 = (const int*)d_in[7];
  const float* mw1 = (const float*)d_in[8];
  const float* mb1 = (const float*)d_in[9];
  const float* mw2 = (const float*)d_in[10];
  const float* mb2 = (const float*)d_in[11];
  const float* lw1 = (const float*)d_in[12];
  const float* lb1 = (const float*)d_in[13];
  const float* lw2 = (const float*)d_in[14];
  const float* lb2 = (const float*)d_in[15];

  const int E1 = in_sizes[0] / 64, E2 = in_sizes[1] / 64;
  const int T = in_sizes[2] / 3;
  const int L = in_sizes[8] / (8 * 64 * 64);
  const size_t nE1 = (size_t)E1 * 64, nE2 = (size_t)E2 * 64;
  const size_t nMax = nE1 > nE2 ? nE1 : nE2;

  // workspace layout (requires E1%16==0 && E2%16==0; true for 150000)
  float* e1b = (float*)d_ws;
  float* e2b = e1b + nE1;
  float* p0 = e2b + nE2;
  float* p1 = p0 + nE1;
  float* mbuf = p1 + nE1;
  const size_t wmat = (size_t)L * 8 * 4096;
  u16* w1h = (u16*)(mbuf + nMax);
  u16* w1l = w1h + wmat;
  u16* w2h = w1l + wmat;
  u16* w2l = w2h + wmat;
  u16* lwh = w2l + wmat;  // 2*4096
  u16* lwl = lwh + 8192;
  const size_t needB = (nE1 * 3 + nE2 + nMax) * 4 + (4 * wmat + 16384) * 2;
  if (ws_size < needB) return;  // insufficient scratch (needs ~193 MB at E=150000)

  // p2/p3 live in d_out (exactly 2*E2*64 floats); dead before final linears write it
  float* p2 = (float*)d_out;
  float* p3 = p2 + nE2;

  const int strips1 = E1 / 16, strips2 = E2 / 16;
  const int mlpB1 = (strips1 + 3) / 4, mlpB2 = (strips2 + 3) / 4;
  const int SEGB = 2048, ELTB = 2048;

  // weight prep
  cvt_split_kernel<<<256, 256, 0, stream>>>(mw1, w1h, w1l, (int)wmat);
  cvt_split_kernel<<<256, 256, 0, stream>>>(mw2, w2h, w2l, (int)wmat);
  cvt_split_kernel<<<32, 256, 0, stream>>>(lw1, lwh, lwl, 4096);
  cvt_split_kernel<<<32, 256, 0, stream>>>(lw2, lwh + 4096, lwl + 4096, 4096);

  // state init
  copy_kernel<<<ELTB, 256, 0, stream>>>(in_e1, e1b, (int)(nE1 / 4));
  copy_kernel<<<ELTB, 256, 0, stream>>>(in_e2, e2b, (int)(nE2 / 4));

  for (int li = 0; li < L; li++) {
    const size_t mo = (size_t)li * 8 * 4096;
    const size_t bo = (size_t)li * 8 * 64;
    // phase 1: e1 update. p0=mlp0(e1) p1=mlp1(e1) p2=mlp2(e2) p3=mlp3(e2)
    mlp_kernel<<<mlpB1, 256, 0, stream>>>(e1b, p0, w1h + mo + 0 * 4096, w1l + mo + 0 * 4096,
                                          w2h + mo + 0 * 4096, w2l + mo + 0 * 4096,
                                          mb1 + bo + 0 * 64, mb2 + bo + 0 * 64, strips1);
    mlp_kernel<<<mlpB1, 256, 0, stream>>>(e1b, p1, w1h + mo + 1 * 4096, w1l + mo + 1 * 4096,
                                          w2h + mo + 1 * 4096, w2l + mo + 1 * 4096,
                                          mb1 + bo + 1 * 64, mb2 + bo + 1 * 64, strips1);
    mlp_kernel<<<mlpB2, 256, 0, stream>>>(e2b, p2, w1h + mo + 2 * 4096, w1l + mo + 2 * 4096,
                                          w2h + mo + 2 * 4096, w2l + mo + 2 * 4096,
                                          mb1 + bo + 2 * 64, mb2 + bo + 2 * 64, strips2);
    mlp_kernel<<<mlpB2, 256, 0, stream>>>(e2b, p3, w1h + mo + 3 * 4096, w1l + mo + 3 * 4096,
                                          w2h + mo + 3 * 4096, w2l + mo + 3 * 4096,
                                          mb1 + bo + 3 * 64, mb2 + bo + 3 * 64, strips2);
    hipMemsetAsync(mbuf, 0, nE1 * 4, stream);
    // m111: e1[ij111] += p0[ik111]*p0[kj111]
    seg_kernel<<<SEGB, 256, 0, stream>>>(e1b, p0, p0, t111, t111 + T, t111 + 2 * T, T);
    // m112 -> mbuf: mbuf[ij112] += p1[ik112]*p2[kj112]
    seg_kernel<<<SEGB, 256, 0, stream>>>(mbuf, p1, p2, t112, t112 + T, t112 + 2 * T, T);
    // m122: e1[ij122] += p3[ik122]*p3[kj122]
    seg_kernel<<<SEGB, 256, 0, stream>>>(e1b, p3, p3, t122, t122 + T, t122 + 2 * T, T);
    // e1 += m112 + m112[inv1]
    addinv_kernel<<<ELTB, 256, 0, stream>>>(e1b, mbuf, inv1, E1);

    // phase 2: e2 update (uses NEW e1 pre-relu, OLD e2). p0=mlp4(e1) p1=mlp5(e1) p2=mlp6(e2) p3=mlp7(e2)
    mlp_kernel<<<mlpB1, 256, 0, stream>>>(e1b, p0, w1h + mo + 4 * 4096, w1l + mo + 4 * 4096,
                                          w2h + mo + 4 * 4096, w2l + mo + 4 * 4096,
                                          mb1 + bo + 4 * 64, mb2 + bo + 4 * 64, strips1);
    mlp_kernel<<<mlpB1, 256, 0, stream>>>(e1b, p1, w1h + mo + 5 * 4096, w1l + mo + 5 * 4096,
                                          w2h + mo + 5 * 4096, w2l + mo + 5 * 4096,
                                          mb1 + bo + 5 * 64, mb2 + bo + 5 * 64, strips1);
    mlp_kernel<<<mlpB2, 256, 0, stream>>>(e2b, p2, w1h + mo + 6 * 4096, w1l + mo + 6 * 4096,
                                          w2h + mo + 6 * 4096, w2l + mo + 6 * 4096,
                                          mb1 + bo + 6 * 64, mb2 + bo + 6 * 64, strips2);
    mlp_kernel<<<mlpB2, 256, 0, stream>>>(e2b, p3, w1h + mo + 7 * 4096, w1l + mo + 7 * 4096,
                                          w2h + mo + 7 * 4096, w2l + mo + 7 * 4096,
                                          mb1 + bo + 7 * 64, mb2 + bo + 7 * 64, strips2);
    hipMemsetAsync(mbuf, 0, nE2 * 4, stream);
    // m211: e2[kj112] += p0[ij112]*p0[ik112]
    seg_kernel<<<SEGB, 256, 0, stream>>>(e2b, p0, p0, t112 + 2 * T, t112, t112 + T, T);
    // m212 -> mbuf: mbuf[ik122] += p1[ij122]*p2[kj122]
    seg_kernel<<<SEGB, 256, 0, stream>>>(mbuf, p1, p2, t122 + T, t122, t122 + 2 * T, T);
    // m222: e2[ij222] += p3[ik222]*p3[kj222]
    seg_kernel<<<SEGB, 256, 0, stream>>>(e2b, p3, p3, t222, t222 + T, t222 + 2 * T, T);
    // e2 += m212 + m212[inv2]
    addinv_kernel<<<ELTB, 256, 0, stream>>>(e2b, mbuf, inv2, E2);

    relu_kernel<<<ELTB, 256, 0, stream>>>(e1b, (int)(nE1 / 4));
    relu_kernel<<<ELTB, 256, 0, stream>>>(e2b, (int)(nE2 / 4));
  }

  // final linears into d_out
  lin_kernel<<<mlpB1, 256, 0, stream>>>(e1b, (float*)d_out, lwh, lwl, lb1, strips1);
  lin_kernel<<<mlpB2, 256, 0, stream>>>(e2b, (float*)d_out + nE1, lwh + 4096, lwl + 4096, lb2, strips2);
}

// Round 2
// 2003.552 us; speedup vs baseline: 1.0236x; 1.0236x over previous
//
#include <hip/hip_runtime.h>

// DR2FWL2 conv, MI355X. Restructuring: mlp(e[idx]) == mlp(e)[idx], so MLPs run once
// over base rows. MLP GEMMs: MFMA 16x16x32 bf16 hi/lo split (~fp32 accuracy).
// R2 change: p-buffers stored fp16 (halves gather bytes in seg phase, halves MLP
// write traffic); relu(e2) fused into phase-2 addinv.
// Segment sums: fp32 global atomics, lane = (triangle, channel).

typedef unsigned short u16;
typedef unsigned int u32;
typedef _Float16 f16;
typedef __attribute__((ext_vector_type(8))) short s16x8;
typedef __attribute__((ext_vector_type(4))) float f32x4;

#define MFMA16(a, b, c) __builtin_amdgcn_mfma_f32_16x16x32_bf16((a), (b), (c), 0, 0, 0)

static __device__ __forceinline__ u16 bf16_rne(float x) {
  u32 u = __float_as_uint(x);
  return (u16)((u + 0x7fffu + ((u >> 16) & 1u)) >> 16);
}
static __device__ __forceinline__ float bf16_f32(u16 h) {
  return __uint_as_float(((u32)h) << 16);
}
// 8 floats (two f32x4) -> hi/lo bf16 fragments
static __device__ __forceinline__ void cvt_hilo8(const f32x4 a, const f32x4 b, s16x8& hi, s16x8& lo) {
#pragma unroll
  for (int j = 0; j < 4; j++) {
    float x = a[j];
    u16 h = bf16_rne(x);
    u16 l = bf16_rne(x - bf16_f32(h));
    hi[j] = (short)h; lo[j] = (short)l;
  }
#pragma unroll
  for (int j = 0; j < 4; j++) {
    float x = b[j];
    u16 h = bf16_rne(x);
    u16 l = bf16_rne(x - bf16_f32(h));
    hi[4 + j] = (short)h; lo[4 + j] = (short)l;
  }
}

// split fp32 weights -> bf16 hi + bf16 lo arrays
__global__ __launch_bounds__(256) void cvt_split_kernel(const float* __restrict__ src,
                                                        u16* __restrict__ hi, u16* __restrict__ lo, int n) {
  int i = blockIdx.x * 256 + threadIdx.x;
  int stride = gridDim.x * 256;
  for (; i < n; i += stride) {
    float x = src[i];
    u16 h = bf16_rne(x);
    hi[i] = h;
    lo[i] = bf16_rne(x - bf16_f32(h));
  }
}

__global__ __launch_bounds__(256) void copy_kernel(const float* __restrict__ src, float* __restrict__ dst, int n4) {
  int i = blockIdx.x * 256 + threadIdx.x;
  int stride = gridDim.x * 256;
  const f32x4* s4 = (const f32x4*)src;
  f32x4* d4 = (f32x4*)dst;
  for (; i < n4; i += stride) d4[i] = s4[i];
}

__global__ __launch_bounds__(256) void relu_kernel(float* __restrict__ e, int n4) {
  int i = blockIdx.x * 256 + threadIdx.x;
  int stride = gridDim.x * 256;
  f32x4* e4 = (f32x4*)e;
  for (; i < n4; i += stride) {
    f32x4 v = e4[i];
#pragma unroll
    for (int j = 0; j < 4; j++) v[j] = fmaxf(v[j], 0.0f);
    e4[i] = v;
  }
}

// e[r] += m[r] + m[inv[r]]  (+ optional relu)  rowwise, float4-vectorized
template <bool DO_RELU>
__global__ __launch_bounds__(256) void addinv_kernel(float* __restrict__ e, const float* __restrict__ m,
                                                     const int* __restrict__ inv, int E) {
  int i = blockIdx.x * 256 + threadIdx.x;
  int stride = gridDim.x * 256;
  int total = E * 16;
  const f32x4* m4 = (const f32x4*)m;
  f32x4* e4 = (f32x4*)e;
  for (; i < total; i += stride) {
    int r = i >> 4, q = i & 15;
    int ir = inv[r];
    f32x4 v = e4[i];
    f32x4 a = m4[i];
    f32x4 b = m4[(size_t)ir * 16 + q];
#pragma unroll
    for (int j = 0; j < 4; j++) {
      float x = v[j] + a[j] + b[j];
      v[j] = DO_RELU ? fmaxf(x, 0.0f) : x;
    }
    e4[i] = v;
  }
}

// dst[id[t]] += pa[ia[t]] * pb[ib[t]]  (64 channels; lane = (triangle, channel))
__global__ __launch_bounds__(256) void seg_kernel(float* __restrict__ dst,
                                                  const f16* __restrict__ pa, const f16* __restrict__ pb,
                                                  const int* __restrict__ id, const int* __restrict__ ia,
                                                  const int* __restrict__ ib, int T) {
  int i = blockIdx.x * 256 + threadIdx.x;
  int stride = gridDim.x * 256;
  int total = T * 64;
  for (; i < total; i += stride) {
    int t = i >> 6, c = i & 63;
    float va = (float)pa[(size_t)ia[t] * 64 + c];
    float vb = (float)pb[(size_t)ib[t] * 64 + c];
    unsafeAtomicAdd(&dst[(size_t)id[t] * 64 + c], va * vb);
  }
}

// Fused 2-layer MLP: dst = relu(src @ W1 + b1) @ W2 + b2, all 64x64, fp16 output.
// One wave per 16-row strip. bf16 hi/lo split => ~fp32 accuracy.
// MFMA fragment layout (m89-verified): A: row=lane&15, k=8*(lane>>4)+j;
// B: col=lane&15, k=8*(lane>>4)+j;  C/D: col=lane&15, row=4*(lane>>4)+reg.
__global__ __launch_bounds__(256) void mlp_kernel(const float* __restrict__ src, f16* __restrict__ dst,
                                                  const u16* __restrict__ w1h_, const u16* __restrict__ w1l_,
                                                  const u16* __restrict__ w2h_, const u16* __restrict__ w2l_,
                                                  const float* __restrict__ b1_, const float* __restrict__ b2_,
                                                  int nstrips) {
  __shared__ float hshm[4][1024];
  const int tid = threadIdx.x;
  const int wave = tid >> 6, lane = tid & 63;
  const int lrow = lane & 15, lk = lane >> 4;

  s16x8 w1h[2][4], w1l[2][4], w2h[2][4], w2l[2][4];
#pragma unroll
  for (int kt = 0; kt < 2; kt++)
#pragma unroll
    for (int nt = 0; nt < 4; nt++) {
      const int n = nt * 16 + lrow;
      const int kb = kt * 32 + lk * 8;
#pragma unroll
      for (int j = 0; j < 8; j++) {
        const int idx = (kb + j) * 64 + n;
        w1h[kt][nt][j] = (short)w1h_[idx];
        w1l[kt][nt][j] = (short)w1l_[idx];
        w2h[kt][nt][j] = (short)w2h_[idx];
        w2l[kt][nt][j] = (short)w2l_[idx];
      }
    }
  float bias1[4], bias2[4];
#pragma unroll
  for (int nt = 0; nt < 4; nt++) {
    bias1[nt] = b1_[nt * 16 + lrow];
    bias2[nt] = b2_[nt * 16 + lrow];
  }

  float* hl = hshm[wave];
  for (int s = blockIdx.x * 4 + wave; s < nstrips; s += gridDim.x * 4) {
    const float* xp = src + (size_t)(s * 16 + lrow) * 64 + lk * 8;
    f32x4 x0 = *(const f32x4*)(xp + 0);
    f32x4 x1 = *(const f32x4*)(xp + 4);
    f32x4 x2 = *(const f32x4*)(xp + 32);
    f32x4 x3 = *(const f32x4*)(xp + 36);
    s16x8 ah[2], al[2];
    cvt_hilo8(x0, x1, ah[0], al[0]);
    cvt_hilo8(x2, x3, ah[1], al[1]);

    f32x4 acc[4];
#pragma unroll
    for (int nt = 0; nt < 4; nt++) { acc[nt][0] = bias1[nt]; acc[nt][1] = bias1[nt]; acc[nt][2] = bias1[nt]; acc[nt][3] = bias1[nt]; }
#pragma unroll
    for (int kt = 0; kt < 2; kt++)
#pragma unroll
      for (int nt = 0; nt < 4; nt++) {
        acc[nt] = MFMA16(ah[kt], w1h[kt][nt], acc[nt]);
        acc[nt] = MFMA16(ah[kt], w1l[kt][nt], acc[nt]);
        acc[nt] = MFMA16(al[kt], w1h[kt][nt], acc[nt]);
      }

    // relu, transpose through per-wave LDS tile (XOR swizzle: conflict-free)
#pragma unroll
    for (int nt = 0; nt < 4; nt++)
#pragma unroll
      for (int r = 0; r < 4; r++) {
        const int row = lk * 4 + r;
        const int col = nt * 16 + lrow;
        hl[row * 64 + (col ^ ((row & 7) << 2))] = fmaxf(acc[nt][r], 0.0f);
      }
    s16x8 bh[2], bl[2];
#pragma unroll
    for (int kt = 0; kt < 2; kt++) {
      const int colb = kt * 32 + lk * 8;
      const int xr = (lrow & 7) << 2;
      f32x4 h0 = *(const f32x4*)&hl[lrow * 64 + ((colb + 0) ^ xr)];
      f32x4 h1 = *(const f32x4*)&hl[lrow * 64 + ((colb + 4) ^ xr)];
      cvt_hilo8(h0, h1, bh[kt], bl[kt]);
    }

    f32x4 out[4];
#pragma unroll
    for (int nt = 0; nt < 4; nt++) { out[nt][0] = bias2[nt]; out[nt][1] = bias2[nt]; out[nt][2] = bias2[nt]; out[nt][3] = bias2[nt]; }
#pragma unroll
    for (int kt = 0; kt < 2; kt++)
#pragma unroll
      for (int nt = 0; nt < 4; nt++) {
        out[nt] = MFMA16(bh[kt], w2h[kt][nt], out[nt]);
        out[nt] = MFMA16(bh[kt], w2l[kt][nt], out[nt]);
        out[nt] = MFMA16(bl[kt], w2h[kt][nt], out[nt]);
      }

    f16* dp = dst + (size_t)s * 1024;
#pragma unroll
    for (int nt = 0; nt < 4; nt++)
#pragma unroll
      for (int r = 0; r < 4; r++)
        dp[(lk * 4 + r) * 64 + nt * 16 + lrow] = (f16)out[nt][r];
  }
}

// Single linear: dst = src @ W + b  (fp32 in/out, no relu)
__global__ __launch_bounds__(256) void lin_kernel(const float* __restrict__ src, float* __restrict__ dst,
                                                  const u16* __restrict__ wh_, const u16* __restrict__ wl_,
                                                  const float* __restrict__ b_, int nstrips) {
  const int tid = threadIdx.x;
  const int wave = tid >> 6, lane = tid & 63;
  const int lrow = lane & 15, lk = lane >> 4;

  s16x8 wh[2][4], wl[2][4];
#pragma unroll
  for (int kt = 0; kt < 2; kt++)
#pragma unroll
    for (int nt = 0; nt < 4; nt++) {
      const int n = nt * 16 + lrow;
      const int kb = kt * 32 + lk * 8;
#pragma unroll
      for (int j = 0; j < 8; j++) {
        const int idx = (kb + j) * 64 + n;
        wh[kt][nt][j] = (short)wh_[idx];
        wl[kt][nt][j] = (short)wl_[idx];
      }
    }
  float bias[4];
#pragma unroll
  for (int nt = 0; nt < 4; nt++) bias[nt] = b_[nt * 16 + lrow];

  for (int s = blockIdx.x * 4 + wave; s < nstrips; s += gridDim.x * 4) {
    const float* xp = src + (size_t)(s * 16 + lrow) * 64 + lk * 8;
    f32x4 x0 = *(const f32x4*)(xp + 0);
    f32x4 x1 = *(const f32x4*)(xp + 4);
    f32x4 x2 = *(const f32x4*)(xp + 32);
    f32x4 x3 = *(const f32x4*)(xp + 36);
    s16x8 ah[2], al[2];
    cvt_hilo8(x0, x1, ah[0], al[0]);
    cvt_hilo8(x2, x3, ah[1], al[1]);

    f32x4 acc[4];
#pragma unroll
    for (int nt = 0; nt < 4; nt++) { acc[nt][0] = bias[nt]; acc[nt][1] = bias[nt]; acc[nt][2] = bias[nt]; acc[nt][3] = bias[nt]; }
#pragma unroll
    for (int kt = 0; kt < 2; kt++)
#pragma unroll
      for (int nt = 0; nt < 4; nt++) {
        acc[nt] = MFMA16(ah[kt], wh[kt][nt], acc[nt]);
        acc[nt] = MFMA16(ah[kt], wl[kt][nt], acc[nt]);
        acc[nt] = MFMA16(al[kt], wh[kt][nt], acc[nt]);
      }
    float* dp = dst + (size_t)s * 1024;
#pragma unroll
    for (int nt = 0; nt < 4; nt++)
#pragma unroll
      for (int r = 0; r < 4; r++)
        dp[(lk * 4 + r) * 64 + nt * 16 + lrow] = acc[nt][r];
  }
}

extern "C" void kernel_launch(void* const* d_in, const int* in_sizes, int n_in,
                              void* d_out, int out_size, void* d_ws, size_t ws_size,
                              hipStream_t stream) {
  const float* in_e1 = (const float*)d_in[0];
  const float* in_e2 = (const float*)d_in[1];
  const int* t111 = (const int*)d_in[2];
  const int* t112 = (const int*)d_in[3];
  const int* t122 = (const int*)d_in[4];
  const int* t222 = (const int*)d_in[5];
  const int* inv1 = (const int*)d_in[6];
  const int* inv2 = (const int*)d_in[7];
  const float* mw1 = (const float*)d_in[8];
  const float* mb1 = (const float*)d_in[9];
  const float* mw2 = (const float*)d_in[10];
  const float* mb2 = (const float*)d_in[11];
  const float* lw1 = (const float*)d_in[12];
  const float* lb1 = (const float*)d_in[13];
  const float* lw2 = (const float*)d_in[14];
  const float* lb2 = (const float*)d_in[15];

  const int E1 = in_sizes[0] / 64, E2 = in_sizes[1] / 64;
  const int T = in_sizes[2] / 3;
  const int L = in_sizes[8] / (8 * 64 * 64);
  const size_t nE1 = (size_t)E1 * 64, nE2 = (size_t)E2 * 64;
  const size_t nMax = nE1 > nE2 ? nE1 : nE2;

  // workspace layout (requires E1%16==0 && E2%16==0)
  float* e1b = (float*)d_ws;
  float* e2b = e1b + nE1;
  float* mbuf = e2b + nE2;
  f16* p0 = (f16*)(mbuf + nMax);
  f16* p1 = p0 + nE1;
  const size_t wmat = (size_t)L * 8 * 4096;
  u16* w1h = (u16*)(p1 + nE1);
  u16* w1l = w1h + wmat;
  u16* w2h = w1l + wmat;
  u16* w2l = w2h + wmat;
  u16* lwh = w2l + wmat;  // 2*4096
  u16* lwl = lwh + 8192;
  const size_t needB = (nE1 + nE2 + nMax) * 4 + 2 * nE1 * 2 + (4 * wmat + 16384) * 2;
  if (ws_size < needB) return;

  // p2/p3 (fp16) live in d_out; dead before final linears write it
  f16* p2 = (f16*)d_out;
  f16* p3 = p2 + nE2;

  const int strips1 = E1 / 16, strips2 = E2 / 16;
  const int mlpB1 = (strips1 + 3) / 4, mlpB2 = (strips2 + 3) / 4;
  const int SEGB = 2048, ELTB = 2048;

  cvt_split_kernel<<<256, 256, 0, stream>>>(mw1, w1h, w1l, (int)wmat);
  cvt_split_kernel<<<256, 256, 0, stream>>>(mw2, w2h, w2l, (int)wmat);
  cvt_split_kernel<<<32, 256, 0, stream>>>(lw1, lwh, lwl, 4096);
  cvt_split_kernel<<<32, 256, 0, stream>>>(lw2, lwh + 4096, lwl + 4096, 4096);

  copy_kernel<<<ELTB, 256, 0, stream>>>(in_e1, e1b, (int)(nE1 / 4));
  copy_kernel<<<ELTB, 256, 0, stream>>>(in_e2, e2b, (int)(nE2 / 4));

  for (int li = 0; li < L; li++) {
    const size_t mo = (size_t)li * 8 * 4096;
    const size_t bo = (size_t)li * 8 * 64;
    // phase 1: e1 update. p0=mlp0(e1) p1=mlp1(e1) p2=mlp2(e2) p3=mlp3(e2)
    mlp_kernel<<<mlpB1, 256, 0, stream>>>(e1b, p0, w1h + mo + 0 * 4096, w1l + mo + 0 * 4096,
                                          w2h + mo + 0 * 4096, w2l + mo + 0 * 4096,
                                          mb1 + bo + 0 * 64, mb2 + bo + 0 * 64, strips1);
    mlp_kernel<<<mlpB1, 256, 0, stream>>>(e1b, p1, w1h + mo + 1 * 4096, w1l + mo + 1 * 4096,
                                          w2h + mo + 1 * 4096, w2l + mo + 1 * 4096,
                                          mb1 + bo + 1 * 64, mb2 + bo + 1 * 64, strips1);
    mlp_kernel<<<mlpB2, 256, 0, stream>>>(e2b, p2, w1h + mo + 2 * 4096, w1l + mo + 2 * 4096,
                                          w2h + mo + 2 * 4096, w2l + mo + 2 * 4096,
                                          mb1 + bo + 2 * 64, mb2 + bo + 2 * 64, strips2);
    mlp_kernel<<<mlpB2, 256, 0, stream>>>(e2b, p3, w1h + mo + 3 * 4096, w1l + mo + 3 * 4096,
                                          w2h + mo + 3 * 4096, w2l + mo + 3 * 4096,
                                          mb1 + bo + 3 * 64, mb2 + bo + 3 * 64, strips2);
    hipMemsetAsync(mbuf, 0, nE1 * 4, stream);
    seg_kernel<<<SEGB, 256, 0, stream>>>(e1b, p0, p0, t111, t111 + T, t111 + 2 * T, T);   // m111
    seg_kernel<<<SEGB, 256, 0, stream>>>(mbuf, p1, p2, t112, t112 + T, t112 + 2 * T, T);  // m112
    seg_kernel<<<SEGB, 256, 0, stream>>>(e1b, p3, p3, t122, t122 + T, t122 + 2 * T, T);   // m122
    addinv_kernel<false><<<ELTB, 256, 0, stream>>>(e1b, mbuf, inv1, E1);

    // phase 2: e2 update (NEW e1 pre-relu, OLD e2). p0=mlp4(e1) p1=mlp5(e1) p2=mlp6(e2) p3=mlp7(e2)
    mlp_kernel<<<mlpB1, 256, 0, stream>>>(e1b, p0, w1h + mo + 4 * 4096, w1l + mo + 4 * 4096,
                                          w2h + mo + 4 * 4096, w2l + mo + 4 * 4096,
                                          mb1 + bo + 4 * 64, mb2 + bo + 4 * 64, strips1);
    mlp_kernel<<<mlpB1, 256, 0, stream>>>(e1b, p1, w1h + mo + 5 * 4096, w1l + mo + 5 * 4096,
                                          w2h + mo + 5 * 4096, w2l + mo + 5 * 4096,
                                          mb1 + bo + 5 * 64, mb2 + bo + 5 * 64, strips1);
    mlp_kernel<<<mlpB2, 256, 0, stream>>>(e2b, p2, w1h + mo + 6 * 4096, w1l + mo + 6 * 4096,
                                          w2h + mo + 6 * 4096, w2l + mo + 6 * 4096,
                                          mb1 + bo + 6 * 64, mb2 + bo + 6 * 64, strips2);
    mlp_kernel<<<mlpB2, 256, 0, stream>>>(e2b, p3, w1h + mo + 7 * 4096, w1l + mo + 7 * 4096,
                                          w2h + mo + 7 * 4096, w2l + mo + 7 * 4096,
                                          mb1 + bo + 7 * 64, mb2 + bo + 7 * 64, strips2);
    hipMemsetAsync(mbuf, 0, nE2 * 4, stream);
    seg_kernel<<<SEGB, 256, 0, stream>>>(e2b, p0, p0, t112 + 2 * T, t112, t112 + T, T);   // m211
    seg_kernel<<<SEGB, 256, 0, stream>>>(mbuf, p1, p2, t122 + T, t122, t122 + 2 * T, T);  // m212
    seg_kernel<<<SEGB, 256, 0, stream>>>(e2b, p3, p3, t222, t222 + T, t222 + 2 * T, T);   // m222
    addinv_kernel<true><<<ELTB, 256, 0, stream>>>(e2b, mbuf, inv2, E2);  // + relu(e2)

    relu_kernel<<<ELTB, 256, 0, stream>>>(e1b, (int)(nE1 / 4));
  }

  lin_kernel<<<mlpB1, 256, 0, stream>>>(e1b, (float*)d_out, lwh, lwl, lb1, strips1);
  lin_kernel<<<mlpB2, 256, 0, stream>>>(e2b, (float*)d_out + nE1, lwh + 4096, lwl + 4096, lb2, strips2);
}

// Round 3
// 991.978 us; speedup vs baseline: 2.0675x; 2.0198x over previous
//
#include <hip/hip_runtime.h>
#include <hip/hip_fp16.h>

// DR2FWL2 conv, MI355X. mlp(e[idx]) == mlp(e)[idx] restructuring; MFMA bf16 hi/lo MLPs.
// R3: (1) packed-fp16 atomics for segment sums (halves atomic op rate - the R2-identified
// limiter), m111/m122 share buffer A, m112/m212 in buffer B, fused e += A + B + B[inv].
// (2) fragment-ordered weight repack: each lane's s16x8 is one coalesced 16B load
// (was 256 scattered 2B loads/thread). (3) 4 MLPs fused per dispatch, 3 segs fused.

typedef unsigned short u16;
typedef unsigned int u32;
typedef _Float16 f16;
typedef __attribute__((ext_vector_type(8))) short s16x8;
typedef __attribute__((ext_vector_type(4))) float f32x4;
typedef __attribute__((ext_vector_type(4))) _Float16 f16x4;

#define MFMA16(a, b, c) __builtin_amdgcn_mfma_f32_16x16x32_bf16((a), (b), (c), 0, 0, 0)

static __device__ __forceinline__ u16 bf16_rne(float x) {
  u32 u = __float_as_uint(x);
  return (u16)((u + 0x7fffu + ((u >> 16) & 1u)) >> 16);
}
static __device__ __forceinline__ float bf16_f32(u16 h) {
  return __uint_as_float(((u32)h) << 16);
}
static __device__ __forceinline__ void cvt_hilo8(const f32x4 a, const f32x4 b, s16x8& hi, s16x8& lo) {
#pragma unroll
  for (int j = 0; j < 4; j++) {
    float x = a[j];
    u16 h = bf16_rne(x);
    u16 l = bf16_rne(x - bf16_f32(h));
    hi[j] = (short)h; lo[j] = (short)l;
  }
#pragma unroll
  for (int j = 0; j < 4; j++) {
    float x = b[j];
    u16 h = bf16_rne(x);
    u16 l = bf16_rne(x - bf16_f32(h));
    hi[4 + j] = (short)h; lo[4 + j] = (short)l;
  }
}

// Repack fp32 [64][64] (k-major) weight matrices into MFMA-fragment-ordered bf16 hi/lo:
// out[((kt*4+nt)*64+lane)*8+j] = w[kt*32+(lane>>4)*8+j][nt*16+(lane&15)]
__global__ __launch_bounds__(256) void repack_split_kernel(const float* __restrict__ src,
                                                           u16* __restrict__ hi, u16* __restrict__ lo, int nmat) {
  int o = blockIdx.x * 256 + threadIdx.x;
  int stride = gridDim.x * 256;
  int total = nmat * 4096;
  for (; o < total; o += stride) {
    int m = o >> 12, r = o & 4095;
    int j = r & 7, lane = (r >> 3) & 63, nt = (r >> 9) & 3, kt = (r >> 11) & 1;
    int k = kt * 32 + ((lane >> 4) << 3) + j;
    int n = nt * 16 + (lane & 15);
    float x = src[(size_t)m * 4096 + k * 64 + n];
    u16 h = bf16_rne(x);
    hi[o] = h;
    lo[o] = bf16_rne(x - bf16_f32(h));
  }
}

__global__ __launch_bounds__(256) void copy_kernel(const float* __restrict__ src, float* __restrict__ dst, int n4) {
  int i = blockIdx.x * 256 + threadIdx.x;
  int stride = gridDim.x * 256;
  const f32x4* s4 = (const f32x4*)src;
  f32x4* d4 = (f32x4*)dst;
  for (; i < n4; i += stride) d4[i] = s4[i];
}

__global__ __launch_bounds__(256) void relu_kernel(float* __restrict__ e, int n4) {
  int i = blockIdx.x * 256 + threadIdx.x;
  int stride = gridDim.x * 256;
  f32x4* e4 = (f32x4*)e;
  for (; i < n4; i += stride) {
    f32x4 v = e4[i];
#pragma unroll
    for (int j = 0; j < 4; j++) v[j] = fmaxf(v[j], 0.0f);
    e4[i] = v;
  }
}

// e[r] += A[r] + B[r] + B[inv[r]]  (+ optional relu); A,B are fp16 m-buffers
template <bool DO_RELU>
__global__ __launch_bounds__(256) void addinv2_kernel(float* __restrict__ e, const f16* __restrict__ A,
                                                      const f16* __restrict__ B, const int* __restrict__ inv, int E) {
  int i = blockIdx.x * 256 + threadIdx.x;
  int stride = gridDim.x * 256;
  int total = E * 16;
  f32x4* e4 = (f32x4*)e;
  const f16x4* A4 = (const f16x4*)A;
  const f16x4* B4 = (const f16x4*)B;
  for (; i < total; i += stride) {
    int r = i >> 4, q = i & 15;
    int ir = inv[r];
    f32x4 v = e4[i];
    f16x4 a = A4[i];
    f16x4 b = B4[i];
    f16x4 bi = B4[(size_t)ir * 16 + q];
#pragma unroll
    for (int j = 0; j < 4; j++) {
      float x = v[j] + (float)a[j] + (float)b[j] + (float)bi[j];
      v[j] = DO_RELU ? fmaxf(x, 0.0f) : x;
    }
    e4[i] = v;
  }
}

// Three fused segment-sums with packed-fp16 atomics. Thread = (triangle, channel-pair).
// seg X: dst[iX0[t]] += paX[iX1[t]] * pbX[iX2[t]]   (A,B,C -> dstA, dstB, dstA)
__global__ __launch_bounds__(256) void seg3_kernel(
    __half2* __restrict__ dstA, __half2* __restrict__ dstB,
    const __half2* __restrict__ paA, const __half2* __restrict__ pbA,
    const int* __restrict__ iA0, const int* __restrict__ iA1, const int* __restrict__ iA2,
    const __half2* __restrict__ paB, const __half2* __restrict__ pbB,
    const int* __restrict__ iB0, const int* __restrict__ iB1, const int* __restrict__ iB2,
    const __half2* __restrict__ paC, const __half2* __restrict__ pbC,
    const int* __restrict__ iC0, const int* __restrict__ iC1, const int* __restrict__ iC2,
    int T) {
  int i = blockIdx.x * 256 + threadIdx.x;
  int stride = gridDim.x * 256;
  int total = 3 * T * 32;
  for (; i < total; i += stride) {
    int u = i >> 5, cp = i & 31;
    __half2* dst;
    const __half2 *pa, *pb;
    const int *i0, *i1, *i2;
    int t;
    if (u < T) { t = u; dst = dstA; pa = paA; pb = pbA; i0 = iA0; i1 = iA1; i2 = iA2; }
    else if (u < 2 * T) { t = u - T; dst = dstB; pa = paB; pb = pbB; i0 = iB0; i1 = iB1; i2 = iB2; }
    else { t = u - 2 * T; dst = dstA; pa = paC; pb = pbC; i0 = iC0; i1 = iC1; i2 = iC2; }
    __half2 va = pa[(size_t)i1[t] * 32 + cp];
    __half2 vb = pb[(size_t)i2[t] * 32 + cp];
    float2 fa = __half22float2(va), fb = __half22float2(vb);
    __half2 prod = __floats2half2_rn(fa.x * fb.x, fa.y * fb.y);
    unsafeAtomicAdd(&dst[(size_t)i0[t] * 32 + cp], prod);
  }
}

// Four fused 2-layer MLPs: dst_mi = relu(src_mi @ W1_mi + b1_mi) @ W2_mi + b2_mi (64x64).
// One wave per 16-row strip; mi 0,1 read srcA (strips s1), mi 2,3 read srcB (strips s2).
// Weights fragment-ordered: lane's s16x8 = one 16B coalesced load.
__global__ __launch_bounds__(256) void mlp4_kernel(
    const float* __restrict__ srcA, const float* __restrict__ srcB,
    f16* __restrict__ d0, f16* __restrict__ d1, f16* __restrict__ d2, f16* __restrict__ d3,
    const u16* __restrict__ w1h_, const u16* __restrict__ w1l_,
    const u16* __restrict__ w2h_, const u16* __restrict__ w2l_,
    const float* __restrict__ b1_, const float* __restrict__ b2_, int s1, int s2) {
  __shared__ float hshm[4][1024];
  const int tid = threadIdx.x;
  const int wave = tid >> 6, lane = tid & 63;
  const int lrow = lane & 15, lk = lane >> 4;
  const int gw = (blockIdx.x * 256 + tid) >> 6;
  const int total = 2 * s1 + 2 * s2;
  if (gw >= total) return;

  int mi, strip;
  const float* src;
  f16* dst;
  if (gw < s1) { mi = 0; strip = gw; src = srcA; dst = d0; }
  else if (gw < 2 * s1) { mi = 1; strip = gw - s1; src = srcA; dst = d1; }
  else if (gw < 2 * s1 + s2) { mi = 2; strip = gw - 2 * s1; src = srcB; dst = d2; }
  else { mi = 3; strip = gw - 2 * s1 - s2; src = srcB; dst = d3; }

  const s16x8* W1H = (const s16x8*)(w1h_ + (size_t)mi * 4096);
  const s16x8* W1L = (const s16x8*)(w1l_ + (size_t)mi * 4096);
  const s16x8* W2H = (const s16x8*)(w2h_ + (size_t)mi * 4096);
  const s16x8* W2L = (const s16x8*)(w2l_ + (size_t)mi * 4096);
  s16x8 w1h[2][4], w1l[2][4], w2h[2][4], w2l[2][4];
#pragma unroll
  for (int kt = 0; kt < 2; kt++)
#pragma unroll
    for (int nt = 0; nt < 4; nt++) {
      const int f = (kt * 4 + nt) * 64 + lane;
      w1h[kt][nt] = W1H[f];
      w1l[kt][nt] = W1L[f];
      w2h[kt][nt] = W2H[f];
      w2l[kt][nt] = W2L[f];
    }
  float bias1[4], bias2[4];
#pragma unroll
  for (int nt = 0; nt < 4; nt++) {
    bias1[nt] = b1_[mi * 64 + nt * 16 + lrow];
    bias2[nt] = b2_[mi * 64 + nt * 16 + lrow];
  }

  float* hl = hshm[wave];
  const float* xp = src + (size_t)(strip * 16 + lrow) * 64 + lk * 8;
  f32x4 x0 = *(const f32x4*)(xp + 0);
  f32x4 x1 = *(const f32x4*)(xp + 4);
  f32x4 x2 = *(const f32x4*)(xp + 32);
  f32x4 x3 = *(const f32x4*)(xp + 36);
  s16x8 ah[2], al[2];
  cvt_hilo8(x0, x1, ah[0], al[0]);
  cvt_hilo8(x2, x3, ah[1], al[1]);

  f32x4 acc[4];
#pragma unroll
  for (int nt = 0; nt < 4; nt++) { acc[nt][0] = bias1[nt]; acc[nt][1] = bias1[nt]; acc[nt][2] = bias1[nt]; acc[nt][3] = bias1[nt]; }
#pragma unroll
  for (int kt = 0; kt < 2; kt++)
#pragma unroll
    for (int nt = 0; nt < 4; nt++) {
      acc[nt] = MFMA16(ah[kt], w1h[kt][nt], acc[nt]);
      acc[nt] = MFMA16(ah[kt], w1l[kt][nt], acc[nt]);
      acc[nt] = MFMA16(al[kt], w1h[kt][nt], acc[nt]);
    }

  // relu + transpose through per-wave LDS tile (XOR swizzle, conflict-free)
#pragma unroll
  for (int nt = 0; nt < 4; nt++)
#pragma unroll
    for (int r = 0; r < 4; r++) {
      const int row = lk * 4 + r;
      const int col = nt * 16 + lrow;
      hl[row * 64 + (col ^ ((row & 7) << 2))] = fmaxf(acc[nt][r], 0.0f);
    }
  s16x8 bh[2], bl[2];
#pragma unroll
  for (int kt = 0; kt < 2; kt++) {
    const int colb = kt * 32 + lk * 8;
    const int xr = (lrow & 7) << 2;
    f32x4 h0 = *(const f32x4*)&hl[lrow * 64 + ((colb + 0) ^ xr)];
    f32x4 h1 = *(const f32x4*)&hl[lrow * 64 + ((colb + 4) ^ xr)];
    cvt_hilo8(h0, h1, bh[kt], bl[kt]);
  }

  f32x4 out[4];
#pragma unroll
  for (int nt = 0; nt < 4; nt++) { out[nt][0] = bias2[nt]; out[nt][1] = bias2[nt]; out[nt][2] = bias2[nt]; out[nt][3] = bias2[nt]; }
#pragma unroll
  for (int kt = 0; kt < 2; kt++)
#pragma unroll
    for (int nt = 0; nt < 4; nt++) {
      out[nt] = MFMA16(bh[kt], w2h[kt][nt], out[nt]);
      out[nt] = MFMA16(bh[kt], w2l[kt][nt], out[nt]);
      out[nt] = MFMA16(bl[kt], w2h[kt][nt], out[nt]);
    }

  f16* dp = dst + (size_t)strip * 1024;
#pragma unroll
  for (int nt = 0; nt < 4; nt++)
#pragma unroll
    for (int r = 0; r < 4; r++)
      dp[(lk * 4 + r) * 64 + nt * 16 + lrow] = (f16)out[nt][r];
}

// Single linear: dst = src @ W + b (fp32 in/out), fragment-ordered weights
__global__ __launch_bounds__(256) void lin_kernel(const float* __restrict__ src, float* __restrict__ dst,
                                                  const u16* __restrict__ wh_, const u16* __restrict__ wl_,
                                                  const float* __restrict__ b_, int nstrips) {
  const int tid = threadIdx.x;
  const int wave = tid >> 6, lane = tid & 63;
  const int lrow = lane & 15, lk = lane >> 4;

  const s16x8* WH = (const s16x8*)wh_;
  const s16x8* WL = (const s16x8*)wl_;
  s16x8 wh[2][4], wl[2][4];
#pragma unroll
  for (int kt = 0; kt < 2; kt++)
#pragma unroll
    for (int nt = 0; nt < 4; nt++) {
      const int f = (kt * 4 + nt) * 64 + lane;
      wh[kt][nt] = WH[f];
      wl[kt][nt] = WL[f];
    }
  float bias[4];
#pragma unroll
  for (int nt = 0; nt < 4; nt++) bias[nt] = b_[nt * 16 + lrow];

  for (int s = blockIdx.x * 4 + wave; s < nstrips; s += gridDim.x * 4) {
    const float* xp = src + (size_t)(s * 16 + lrow) * 64 + lk * 8;
    f32x4 x0 = *(const f32x4*)(xp + 0);
    f32x4 x1 = *(const f32x4*)(xp + 4);
    f32x4 x2 = *(const f32x4*)(xp + 32);
    f32x4 x3 = *(const f32x4*)(xp + 36);
    s16x8 ah[2], al[2];
    cvt_hilo8(x0, x1, ah[0], al[0]);
    cvt_hilo8(x2, x3, ah[1], al[1]);

    f32x4 acc[4];
#pragma unroll
    for (int nt = 0; nt < 4; nt++) { acc[nt][0] = bias[nt]; acc[nt][1] = bias[nt]; acc[nt][2] = bias[nt]; acc[nt][3] = bias[nt]; }
#pragma unroll
    for (int kt = 0; kt < 2; kt++)
#pragma unroll
      for (int nt = 0; nt < 4; nt++) {
        acc[nt] = MFMA16(ah[kt], wh[kt][nt], acc[nt]);
        acc[nt] = MFMA16(ah[kt], wl[kt][nt], acc[nt]);
        acc[nt] = MFMA16(al[kt], wh[kt][nt], acc[nt]);
      }
    float* dp = dst + (size_t)s * 1024;
#pragma unroll
    for (int nt = 0; nt < 4; nt++)
#pragma unroll
      for (int r = 0; r < 4; r++)
        dp[(lk * 4 + r) * 64 + nt * 16 + lrow] = acc[nt][r];
  }
}

extern "C" void kernel_launch(void* const* d_in, const int* in_sizes, int n_in,
                              void* d_out, int out_size, void* d_ws, size_t ws_size,
                              hipStream_t stream) {
  const float* in_e1 = (const float*)d_in[0];
  const float* in_e2 = (const float*)d_in[1];
  const int* t111 = (const int*)d_in[2];
  const int* t112 = (const int*)d_in[3];
  const int* t122 = (const int*)d_in[4];
  const int* t222 = (const int*)d_in[5];
  const int* inv1 = (const int*)d_in[6];
  const int* inv2 = (const int*)d_in[7];
  const float* mw1 = (const float*)d_in[8];
  const float* mb1 = (const float*)d_in[9];
  const float* mw2 = (const float*)d_in[10];
  const float* mb2 = (const float*)d_in[11];
  const float* lw1 = (const float*)d_in[12];
  const float* lb1 = (const float*)d_in[13];
  const float* lw2 = (const float*)d_in[14];
  const float* lb2 = (const float*)d_in[15];

  const int E1 = in_sizes[0] / 64, E2 = in_sizes[1] / 64;
  const int T = in_sizes[2] / 3;
  const int L = in_sizes[8] / (8 * 64 * 64);
  const size_t nE1 = (size_t)E1 * 64, nE2 = (size_t)E2 * 64;
  const size_t nMax = nE1 > nE2 ? nE1 : nE2;

  // workspace: e1b,e2b fp32; mA,mB,p0,p1 fp16; weights bf16 hi/lo (fragment-ordered)
  float* e1b = (float*)d_ws;
  float* e2b = e1b + nE1;
  f16* mA = (f16*)(e2b + nE2);
  f16* mB = mA + nMax;
  f16* p0 = mB + nMax;
  f16* p1 = p0 + nE1;
  const size_t wmat = (size_t)L * 8 * 4096;
  u16* w1h = (u16*)(p1 + nE1);
  u16* w1l = w1h + wmat;
  u16* w2h = w1l + wmat;
  u16* w2l = w2h + wmat;
  u16* lwh = w2l + wmat;  // 2 matrices
  u16* lwl = lwh + 8192;
  const size_t needB = (nE1 + nE2) * 4 + (2 * nMax + 2 * nE1) * 2 + (4 * wmat + 4 * 4096) * 2;
  if (ws_size < needB) return;

  // p2/p3 (fp16) live in d_out; dead before the final linears write it
  f16* p2 = (f16*)d_out;
  f16* p3 = p2 + nE2;

  const int s1 = E1 / 16, s2 = E2 / 16;
  const int mlp4B = (2 * s1 + 2 * s2 + 3) / 4;
  const int SEGB = 2048, ELTB = 2048;

  repack_split_kernel<<<256, 256, 0, stream>>>(mw1, w1h, w1l, L * 8);
  repack_split_kernel<<<256, 256, 0, stream>>>(mw2, w2h, w2l, L * 8);
  repack_split_kernel<<<32, 256, 0, stream>>>(lw1, lwh, lwl, 1);
  repack_split_kernel<<<32, 256, 0, stream>>>(lw2, lwh + 4096, lwl + 4096, 1);

  copy_kernel<<<ELTB, 256, 0, stream>>>(in_e1, e1b, (int)(nE1 / 4));
  copy_kernel<<<ELTB, 256, 0, stream>>>(in_e2, e2b, (int)(nE2 / 4));

  for (int li = 0; li < L; li++) {
    const size_t mo = (size_t)li * 8 * 4096;
    const size_t bo = (size_t)li * 8 * 64;
    // phase 1: e1 update. p0=mlp0(e1) p1=mlp1(e1) p2=mlp2(e2) p3=mlp3(e2)
    mlp4_kernel<<<mlp4B, 256, 0, stream>>>(e1b, e2b, p0, p1, p2, p3,
                                           w1h + mo, w1l + mo, w2h + mo, w2l + mo,
                                           mb1 + bo, mb2 + bo, s1, s2);
    hipMemsetAsync(mA, 0, 2 * nMax * 2, stream);  // clears mA and mB
    // A: m111 (->mA), B: m112 (->mB), C: m122 (->mA)
    seg3_kernel<<<SEGB, 256, 0, stream>>>(
        (__half2*)mA, (__half2*)mB,
        (const __half2*)p0, (const __half2*)p0, t111, t111 + T, t111 + 2 * T,
        (const __half2*)p1, (const __half2*)p2, t112, t112 + T, t112 + 2 * T,
        (const __half2*)p3, (const __half2*)p3, t122, t122 + T, t122 + 2 * T, T);
    addinv2_kernel<false><<<ELTB, 256, 0, stream>>>(e1b, mA, mB, inv1, E1);

    // phase 2: e2 update (NEW e1 pre-relu, OLD e2). p0=mlp4(e1) p1=mlp5(e1) p2=mlp6(e2) p3=mlp7(e2)
    mlp4_kernel<<<mlp4B, 256, 0, stream>>>(e1b, e2b, p0, p1, p2, p3,
                                           w1h + mo + 4 * 4096, w1l + mo + 4 * 4096,
                                           w2h + mo + 4 * 4096, w2l + mo + 4 * 4096,
                                           mb1 + bo + 4 * 64, mb2 + bo + 4 * 64, s1, s2);
    hipMemsetAsync(mA, 0, 2 * nMax * 2, stream);
    // A: m211 (->mA), B: m212 (->mB), C: m222 (->mA)
    seg3_kernel<<<SEGB, 256, 0, stream>>>(
        (__half2*)mA, (__half2*)mB,
        (const __half2*)p0, (const __half2*)p0, t112 + 2 * T, t112, t112 + T,
        (const __half2*)p1, (const __half2*)p2, t122 + T, t122, t122 + 2 * T,
        (const __half2*)p3, (const __half2*)p3, t222, t222 + T, t222 + 2 * T, T);
    addinv2_kernel<true><<<ELTB, 256, 0, stream>>>(e2b, mA, mB, inv2, E2);  // + relu(e2)

    relu_kernel<<<ELTB, 256, 0, stream>>>(e1b, (int)(nE1 / 4));
  }

  lin_kernel<<<(s1 + 3) / 4, 256, 0, stream>>>(e1b, (float*)d_out, lwh, lwl, lb1, s1);
  lin_kernel<<<(s2 + 3) / 4, 256, 0, stream>>>(e2b, (float*)d_out + nE1, lwh + 4096, lwl + 4096, lb2, s2);
}